// Round 11
// baseline (209.129 us; speedup 1.0000x reference)
//
#include <hip/hip_runtime.h>
#include <cstdint>
#include <cstddef>

#define NBm 256
#define NAm 96
#define NDm 384
#define NHm 192
#define NFm 96
#define NSm 4
#define NATOMS (NBm*NAm)      /* 24576 */
#define NEe (NATOMS*32)       /* 786432 */
#define NMSG (2*NEe)          /* 1572864 */
#define HBLK 1536             /* NMSG / 1024 */
#define CUTOFF_ 5.2f

typedef __attribute__((ext_vector_type(8))) short short8;
typedef __attribute__((ext_vector_type(4))) float float4v;
typedef __attribute__((ext_vector_type(2))) int int2v;

__device__ __forceinline__ short f2bf(float f){
  union { float f; unsigned u; } v; v.f = f;
  unsigned r = v.u + 0x7FFFu + ((v.u >> 16) & 1u);
  return (short)(r >> 16);
}

// jax.nn.gelu default: tanh approximation
__device__ __forceinline__ float gelu_t(float x){
  float u = 0.7978845608028654f * (x + 0.044715f * x*x*x);
  float e = __expf(-2.0f * fabsf(u));
  float t = (1.0f - e) / (1.0f + e);
  t = (u >= 0.f) ? t : -t;
  return 0.5f * x * (1.0f + t);
}

// ---------- weight prep: f32 -> bf16 transposed [s][col][k] ----------
#define W1N (NSm*NDm*NHm)   /* 294912 */
#define W2N (NSm*NHm*NFm)   /* 73728 */
#define WNN (NSm*NFm*NFm)   /* 36864 */
__global__ void k_wprep(const float* __restrict__ W1, const float* __restrict__ W2,
                        const float* __restrict__ Wn,
                        short* __restrict__ W1t, short* __restrict__ W2t,
                        short* __restrict__ Wnt){
  int idx = blockIdx.x*256 + threadIdx.x;
  if (idx < W1N){
    int s = idx / (NDm*NHm); int rem = idx - s*NDm*NHm;
    int k = rem / NHm, c = rem - k*NHm;
    W1t[(s*NHm + c)*NDm + k] = f2bf(W1[idx]);
  } else if (idx < W1N + W2N){
    int j = idx - W1N;
    int s = j / (NHm*NFm); int rem = j - s*NHm*NFm;
    int k = rem / NFm, c = rem - k*NFm;
    W2t[(s*NFm + c)*NHm + k] = f2bf(W2[j]);
  } else if (idx < W1N + W2N + WNN){
    int j = idx - W1N - W2N;
    int s = j / (NFm*NFm); int rem = j - s*NFm*NFm;
    int k = rem / NFm, c = rem - k*NFm;
    Wnt[(s*NFm + c)*NFm + k] = f2bf(Wn[j]);
  }
}

// ---------- fused species count + scan (single block) ----------
__global__ void k_spinit(const int* __restrict__ sp, int* __restrict__ sps,
                         int* __restrict__ spcur){
  __shared__ int h[NSm];
  int t = threadIdx.x;
  if (t < NSm) h[t] = 0;
  __syncthreads();
  for (int i = t; i < NATOMS; i += 1024) atomicAdd(&h[sp[i]], 1);
  __syncthreads();
  if (t == 0){
    int r = 0;
    for (int s=0;s<NSm;s++){ sps[s]=r; spcur[s]=r; r += h[s]; }
    sps[NSm] = r;
  }
}

__global__ void k_spscatter(const int* __restrict__ sp, int* __restrict__ spcur,
                            int* __restrict__ order){
  __shared__ int h[NSm], base[NSm];
  int t = threadIdx.x;
  if (t < NSm) h[t]=0;
  __syncthreads();
  int i = blockIdx.x*256 + t;
  int s = sp[i];
  int lr = atomicAdd(&h[s], 1);
  __syncthreads();
  if (t < NSm) base[t] = atomicAdd(&spcur[t], h[t]);
  __syncthreads();
  order[base[s] + lr] = i;
}

// ---------- fused per-species MLP + epilogue A; 32-row tiles, column-split waves ----------
// internal = gelu(X@W1)@W2 ; nbr = internal@Wn (stored f32)
// pre[i] = dot(internal_i, Wf[s][0:96])
// 32 rows/block, 4 waves: wave w -> rows (w&1)*16..+15, column-half (w>>1).
// Staging: R8-verified single-buffer Ws, 2 barriers/chunk, values bit-identical.
// Grid = NATOMS/32 working blocks (2x R10) -> ~3 blocks/CU, 12 waves/CU.
__global__ __launch_bounds__(256) void k_mlp(
    const float* __restrict__ X, const int* __restrict__ order,
    const int* __restrict__ sps,
    const short* __restrict__ W1t, const short* __restrict__ W2t,
    const short* __restrict__ Wnt, const float* __restrict__ Wf,
    float* __restrict__ pre, float* __restrict__ nbr_g){
  const int s = blockIdx.y;
  const int s0 = sps[s];
  const int cnt = sps[s+1] - s0;
  const int row0 = blockIdx.x * 32;
  if (row0 >= cnt) return;

  __shared__ short Hs[32][200];
  __shared__ short Ws[192*40];
  __shared__ short Is[32][104];
  __shared__ int aids[32];
  __shared__ float preP[32][2];

  const int tid = threadIdx.x;
  if (tid < 32){
    int r = row0 + tid;
    aids[tid] = order[s0 + ((r < cnt) ? r : 0)];
  }
  __syncthreads();

  const int wave = tid >> 6, lane = tid & 63;
  const int lrow = lane & 15, quad = lane >> 4;
  const int rg = wave & 1, cg = wave >> 1;
  const int arow = rg*16 + lrow;
  const float* xrow = X + (size_t)aids[arow]*NDm + quad*8;

  // preload & convert all A fragments (GEMM1) up front
  short8 afs[12];
  #pragma unroll
  for (int kb=0; kb<12; kb++){
    const float* p = xrow + kb*32;
    #pragma unroll
    for (int j=0;j<8;j++) afs[kb][j] = f2bf(p[j]);
  }

  // ---- GEMM1: [32,384]@[384,192]; wave covers 96 cols (6 ct tiles)
  const short* W1s = W1t + (size_t)s*NHm*NDm;
  float4v acc[6];
  #pragma unroll
  for (int i=0;i<6;i++){ acc[i][0]=0.f; acc[i][1]=0.f; acc[i][2]=0.f; acc[i][3]=0.f; }
  for (int kb=0; kb<12; kb++){
    __syncthreads();
    for (int e = tid; e < 192*4; e += 256){
      int c = e >> 2, kq = (e & 3) * 8;
      *(short8*)(&Ws[c*40 + kq]) = *(const short8*)(W1s + c*NDm + kb*32 + kq);
    }
    __syncthreads();
    short8 af = afs[kb];
    #pragma unroll
    for (int ct=0; ct<6; ct++){
      short8 bfb = *(const short8*)(&Ws[(cg*96 + ct*16 + lrow)*40 + quad*8]);
      acc[ct] = __builtin_amdgcn_mfma_f32_16x16x32_bf16(af, bfb, acc[ct], 0,0,0);
    }
  }
  #pragma unroll
  for (int ct=0; ct<6; ct++){
    #pragma unroll
    for (int r=0;r<4;r++){
      Hs[rg*16 + quad*4 + r][cg*96 + ct*16 + lrow] = f2bf(gelu_t(acc[ct][r]));
    }
  }

  // ---- GEMM2: [32,192]@[192,96]; wave covers 48 cols (3 ct tiles)
  // (first staging barrier below also orders the Hs writes above)
  const short* W2s = W2t + (size_t)s*NFm*NHm;
  float4v acc2[3];
  #pragma unroll
  for (int i=0;i<3;i++){ acc2[i][0]=0.f; acc2[i][1]=0.f; acc2[i][2]=0.f; acc2[i][3]=0.f; }
  for (int kb=0; kb<6; kb++){
    __syncthreads();
    for (int e = tid; e < 96*4; e += 256){
      int c = e >> 2, kq = (e & 3) * 8;
      *(short8*)(&Ws[c*40 + kq]) = *(const short8*)(W2s + c*NHm + kb*32 + kq);
    }
    __syncthreads();
    short8 af2 = *(const short8*)(&Hs[rg*16 + lrow][kb*32 + quad*8]);
    #pragma unroll
    for (int ct=0; ct<3; ct++){
      short8 bfb = *(const short8*)(&Ws[(cg*48 + ct*16 + lrow)*40 + quad*8]);
      acc2[ct] = __builtin_amdgcn_mfma_f32_16x16x32_bf16(af2, bfb, acc2[ct], 0,0,0);
    }
  }
  // internal -> Is (bf16)
  #pragma unroll
  for (int ct=0; ct<3; ct++){
    #pragma unroll
    for (int r=0;r<4;r++){
      Is[rg*16 + quad*4 + r][cg*48 + ct*16 + lrow] = f2bf(acc2[ct][r]);
    }
  }

  // ---- epilogue A: per-wave partial dot over its 48 cols, combine halves via LDS
  {
    float pr[4] = {0.f,0.f,0.f,0.f};
    #pragma unroll
    for (int ct=0; ct<3; ct++){
      float wv = Wf[s*2*NFm + cg*48 + ct*16 + lrow];
      #pragma unroll
      for (int r=0;r<4;r++) pr[r] += acc2[ct][r] * wv;
    }
    #pragma unroll
    for (int m=1; m<16; m<<=1){
      #pragma unroll
      for (int r=0;r<4;r++) pr[r] += __shfl_xor(pr[r], m, 64);
    }
    if (lrow == 0){
      #pragma unroll
      for (int r=0;r<4;r++) preP[rg*16 + quad*4 + r][cg] = pr[r];
    }
  }
  __syncthreads();
  if (tid < 32){
    if (row0 + tid < cnt) pre[aids[tid]] = preP[tid][0] + preP[tid][1];
  }

  // ---- GEMM3: [32,96]@[96,96]; wave covers 48 cols (3 ct tiles)
  const short* Wns = Wnt + (size_t)s*NFm*NFm;
  float4v acc3[3];
  #pragma unroll
  for (int i=0;i<3;i++){ acc3[i][0]=0.f; acc3[i][1]=0.f; acc3[i][2]=0.f; acc3[i][3]=0.f; }
  for (int kb=0; kb<3; kb++){
    __syncthreads();
    for (int e = tid; e < 96*4; e += 256){
      int c = e >> 2, kq = (e & 3) * 8;
      *(short8*)(&Ws[c*40 + kq]) = *(const short8*)(Wns + c*NFm + kb*32 + kq);
    }
    __syncthreads();
    short8 af3 = *(const short8*)(&Is[rg*16 + lrow][kb*32 + quad*8]);
    #pragma unroll
    for (int ct=0; ct<3; ct++){
      short8 bfb = *(const short8*)(&Ws[(cg*48 + ct*16 + lrow)*40 + quad*8]);
      acc3[ct] = __builtin_amdgcn_mfma_f32_16x16x32_bf16(af3, bfb, acc3[ct], 0,0,0);
    }
  }
  #pragma unroll
  for (int ct=0; ct<3; ct++){
    #pragma unroll
    for (int r=0;r<4;r++){
      int row = rg*16 + quad*4 + r, col = cg*48 + ct*16 + lrow;
      if (row0 + row < cnt) nbr_g[(size_t)aids[row]*NFm + col] = acc3[ct][r];
    }
  }
}

// ---------- per-atom nd4: one wave per atom, xor-shuffle reduce (verified R4-R10) ----------
// nd4[i][s'] = dot(nbr[i], Wf[s'][96:192])  for s'=0..3
__global__ void k_nd4(const float* __restrict__ nbr, const float* __restrict__ Wf,
                      float* __restrict__ nd4){
  int a = blockIdx.x*4 + (threadIdx.x >> 6);   // grid = NATOMS/4 exact
  int lane = threadIdx.x & 63;
  bool lo = lane < 32;
  const float* np = nbr + (size_t)a*NFm;
  float nv1 = np[lane];
  float nv2 = lo ? np[64+lane] : 0.f;
  const float* w0 = Wf + 0*2*NFm + NFm;
  const float* w1 = Wf + 1*2*NFm + NFm;
  const float* w2 = Wf + 2*2*NFm + NFm;
  const float* w3 = Wf + 3*2*NFm + NFm;
  float n0 = nv1*w0[lane] + (lo ? nv2*w0[64+lane] : 0.f);
  float n1 = nv1*w1[lane] + (lo ? nv2*w1[64+lane] : 0.f);
  float n2 = nv1*w2[lane] + (lo ? nv2*w2[64+lane] : 0.f);
  float n3 = nv1*w3[lane] + (lo ? nv2*w3[64+lane] : 0.f);
  #pragma unroll
  for (int m=1; m<64; m<<=1){
    n0 += __shfl_xor(n0, m, 64);
    n1 += __shfl_xor(n1, m, 64);
    n2 += __shfl_xor(n2, m, 64);
    n3 += __shfl_xor(n3, m, 64);
  }
  if (lane == 0){
    float4v v; v[0]=n0; v[1]=n1; v[2]=n2; v[3]=n3;
    *(float4v*)(nd4 + (size_t)a*4) = v;
  }
}

// ---------- message histogram by destination molecule (no global atomics) ----------
__global__ __launch_bounds__(1024) void k_hist(const int* __restrict__ ai,
                                               int* __restrict__ Hist){
  __shared__ int h[NBm];
  int t = threadIdx.x;
  if (t < NBm) h[t] = 0;
  __syncthreads();
  int m = blockIdx.x*1024 + t;        // m in [0, NMSG), grid = HBLK exact
  int mol = ai[m] / NAm;
  atomicAdd(&h[mol], 1);
  __syncthreads();
  if (t < NBm) Hist[blockIdx.x*NBm + t] = h[t];
}

// ---------- per-molecule scan over blocks; Hist overwritten with excl prefix ----------
__global__ void k_mscan(int* __restrict__ Hist, int* __restrict__ Tot){
  __shared__ int sums[256];
  int mol = blockIdx.x, t = threadIdx.x;
  int v[6]; int loc = 0;
  #pragma unroll
  for (int j=0;j<6;j++){ v[j] = Hist[(t*6+j)*NBm + mol]; loc += v[j]; }
  sums[t] = loc; __syncthreads();
  for (int off=1; off<256; off<<=1){
    int x = (t >= off) ? sums[t-off] : 0;
    __syncthreads();
    sums[t] += x;
    __syncthreads();
  }
  int run = sums[t] - loc;
  #pragma unroll
  for (int j=0;j<6;j++){ Hist[(t*6+j)*NBm + mol] = run; run += v[j]; }
  if (t == 255) Tot[mol] = run;
}

// ---------- exclusive scan of molecule totals ----------
__global__ void k_segscan(const int* __restrict__ Tot, int* __restrict__ Seg){
  __shared__ int s[256];
  int t = threadIdx.x;
  int v = Tot[t]; s[t] = v; __syncthreads();
  for (int off=1; off<256; off<<=1){
    int x = (t >= off) ? s[t-off] : 0;
    __syncthreads();
    s[t] += x;
    __syncthreads();
  }
  Seg[t] = s[t] - v;
  if (t == 255) Seg[256] = s[255];
}

// ---------- scatter messages into molecule segments (no global atomics) ----------
// Msg[pos] = { (other<<7) | dest_local , w }
__global__ __launch_bounds__(1024) void k_scatter(const int* __restrict__ ai,
    const float* __restrict__ dist, const float* __restrict__ pref,
    const float* __restrict__ fac, const int* __restrict__ Hist,
    const int* __restrict__ Seg, int2v* __restrict__ Msg){
  __shared__ int cnt[NBm];
  __shared__ int off[NBm];
  int t = threadIdx.x;
  if (t < NBm){ cnt[t] = 0; off[t] = Seg[t] + Hist[blockIdx.x*NBm + t]; }
  __syncthreads();
  int m = blockIdx.x*1024 + t;
  int dest = ai[m];
  int other = ai[(m < NEe) ? m + NEe : m - NEe];
  int e = (m < NEe) ? m : m - NEe;
  float d = dist[e];
  float x = (CUTOFF_ - d) * (1.0f/CUTOFF_);
  x = fminf(fmaxf(x, 0.f), 1.f);
  float sc = x*x*x*(x*(6.f*x - 15.f) + 10.f);
  float p = pref[0], fc = fac[0];
  float w = p*p * expf(-fc*fc*d) * sc;
  int mol = dest / NAm, dl = dest - mol*NAm;
  int rank = atomicAdd(&cnt[mol], 1);
  int2v msg; msg[0] = (other << 7) | dl; msg[1] = __float_as_int(w);
  Msg[off[mol] + rank] = msg;
}

// ---------- per-molecule accumulate + charge redistribution (fused finalize) ----------
__global__ __launch_bounds__(256) void k_accum(const int* __restrict__ Seg,
    const int2v* __restrict__ Msg, const float* __restrict__ nd4,
    const int* __restrict__ sp, const float* __restrict__ pre,
    const float* __restrict__ tc, float* __restrict__ out){
  __shared__ float acc[NAm];
  __shared__ int spl[NAm];
  __shared__ float red[128];
  int mol = blockIdx.x, t = threadIdx.x;
  if (t < NAm){ acc[t] = 0.f; spl[t] = sp[mol*NAm + t]; }
  __syncthreads();
  int s0 = Seg[mol], s1 = Seg[mol+1];
  for (int i = s0 + t; i < s1; i += 256){
    int2v kw = Msg[i];
    int key = kw[0]; float w = __int_as_float(kw[1]);
    int dl = key & 127, other = key >> 7;
    float val = w * nd4[(size_t)other*4 + spl[dl]];
    atomicAdd(&acc[dl], val);
  }
  __syncthreads();
  float pch = 0.f;
  if (t < NAm) pch = pre[mol*NAm + t] + acc[t];
  if (t < 128) red[t] = (t < NAm) ? pch : 0.f;
  __syncthreads();
  for (int o=64; o>0; o>>=1){
    if (t < o) red[t] += red[t + o];
    __syncthreads();
  }
  float sum = red[0];
  if (t < NAm){
    float c = pch + (tc[mol] - sum) * (1.0f/96.0f);
    out[mol*NAm + t] = (float)spl[t];            // species as float
    out[NATOMS + mol*NAm + t] = c;               // charges
    out[2*NATOMS + mol*NAm + t] = pch;           // precharges
  }
}

extern "C" void kernel_launch(void* const* d_in, const int* in_sizes, int n_in,
                              void* d_out, int out_size, void* d_ws, size_t ws_size,
                              hipStream_t stream) {
  const int*   species = (const int*)  d_in[0];
  const float* X       = (const float*)d_in[1];
  const int*   ai      = (const int*)  d_in[2];
  const float* dist    = (const float*)d_in[3];
  const float* tc      = (const float*)d_in[4];
  const float* W1      = (const float*)d_in[5];
  const float* W2      = (const float*)d_in[6];
  const float* Wn      = (const float*)d_in[7];
  const float* Wf      = (const float*)d_in[8];
  const float* pref    = (const float*)d_in[9];
  const float* fac     = (const float*)d_in[10];
  float* out = (float*)d_out;

  char* w = (char*)d_ws;
  auto alloc = [&](size_t bytes)->char*{
    char* p = w; w += (bytes + 255) & ~(size_t)255; return p;
  };
  int*   sps   = (int*)  alloc(64);
  int*   spcur = (int*)  alloc(64);
  int*   order = (int*)  alloc((size_t)NATOMS*4);
  float* nd4   = (float*)alloc((size_t)NATOMS*4*4);
  float* pre   = (float*)alloc((size_t)NATOMS*4);
  float* nbr   = (float*)alloc((size_t)NATOMS*NFm*4);
  short* W1t   = (short*)alloc((size_t)W1N*2);
  short* W2t   = (short*)alloc((size_t)W2N*2);
  short* Wnt   = (short*)alloc((size_t)WNN*2);
  int*   Hist  = (int*)  alloc((size_t)HBLK*NBm*4);
  int*   Tot   = (int*)  alloc(1024);
  int*   Seg   = (int*)  alloc((NBm+1)*4);
  int2v* Msg   = (int2v*)alloc((size_t)NMSG*8);

  k_wprep<<<(W1N+W2N+WNN)/256, 256, 0, stream>>>(W1, W2, Wn, W1t, W2t, Wnt);
  k_spinit<<<1, 1024, 0, stream>>>(species, sps, spcur);
  k_spscatter<<<NATOMS/256, 256, 0, stream>>>(species, spcur, order);
  dim3 g(NATOMS/32, NSm);
  k_mlp<<<g, 256, 0, stream>>>(X, order, sps, W1t, W2t, Wnt, Wf, pre, nbr);
  k_nd4<<<NATOMS/4, 256, 0, stream>>>(nbr, Wf, nd4);
  k_hist<<<HBLK, 1024, 0, stream>>>(ai, Hist);
  k_mscan<<<NBm, 256, 0, stream>>>(Hist, Tot);
  k_segscan<<<1, 256, 0, stream>>>(Tot, Seg);
  k_scatter<<<HBLK, 1024, 0, stream>>>(ai, dist, pref, fac, Hist, Seg, Msg);
  k_accum<<<NBm, 256, 0, stream>>>(Seg, Msg, nd4, species, pre, tc, out);
}

// Round 12
// 183.946 us; speedup vs baseline: 1.1369x; 1.1369x over previous
//
#include <hip/hip_runtime.h>
#include <cstdint>
#include <cstddef>

#define NBm 256
#define NAm 96
#define NDm 384
#define NHm 192
#define NFm 96
#define NSm 4
#define NATOMS (NBm*NAm)      /* 24576 */
#define NEe (NATOMS*32)       /* 786432 */
#define NMSG (2*NEe)          /* 1572864 */
#define HBLK2 768             /* NMSG / 2048 */
#define CUTOFF_ 5.2f

typedef __attribute__((ext_vector_type(8))) short short8;
typedef __attribute__((ext_vector_type(4))) float float4v;
typedef __attribute__((ext_vector_type(2))) int int2v;

__device__ __forceinline__ short f2bf(float f){
  union { float f; unsigned u; } v; v.f = f;
  unsigned r = v.u + 0x7FFFu + ((v.u >> 16) & 1u);
  return (short)(r >> 16);
}

// jax.nn.gelu default: tanh approximation
__device__ __forceinline__ float gelu_t(float x){
  float u = 0.7978845608028654f * (x + 0.044715f * x*x*x);
  float e = __expf(-2.0f * fabsf(u));
  float t = (1.0f - e) / (1.0f + e);
  t = (u >= 0.f) ? t : -t;
  return 0.5f * x * (1.0f + t);
}

// ---------- weight prep: f32 -> bf16 transposed [s][col][k]; zeros spc ----------
#define W1N (NSm*NDm*NHm)   /* 294912 */
#define W2N (NSm*NHm*NFm)   /* 73728 */
#define WNN (NSm*NFm*NFm)   /* 36864 */
__global__ void k_wprep(const float* __restrict__ W1, const float* __restrict__ W2,
                        const float* __restrict__ Wn,
                        short* __restrict__ W1t, short* __restrict__ W2t,
                        short* __restrict__ Wnt, int* __restrict__ spc){
  if (blockIdx.x == 0 && threadIdx.x < NSm) spc[threadIdx.x] = 0;
  int idx = blockIdx.x*256 + threadIdx.x;
  if (idx < W1N){
    int s = idx / (NDm*NHm); int rem = idx - s*NDm*NHm;
    int k = rem / NHm, c = rem - k*NHm;
    W1t[(s*NHm + c)*NDm + k] = f2bf(W1[idx]);
  } else if (idx < W1N + W2N){
    int j = idx - W1N;
    int s = j / (NHm*NFm); int rem = j - s*NHm*NFm;
    int k = rem / NFm, c = rem - k*NFm;
    W2t[(s*NFm + c)*NHm + k] = f2bf(W2[j]);
  } else if (idx < W1N + W2N + WNN){
    int j = idx - W1N - W2N;
    int s = j / (NFm*NFm); int rem = j - s*NFm*NFm;
    int k = rem / NFm, c = rem - k*NFm;
    Wnt[(s*NFm + c)*NFm + k] = f2bf(Wn[j]);
  }
}

__global__ void k_spcount(const int* __restrict__ sp, int* __restrict__ spc){
  __shared__ int h[NSm];
  int t = threadIdx.x;
  if (t < NSm) h[t] = 0;
  __syncthreads();
  int i = blockIdx.x*256 + t;     // grid = 96 exact
  atomicAdd(&h[sp[i]], 1);
  __syncthreads();
  if (t < NSm) atomicAdd(&spc[t], h[t]);
}

__global__ void k_spscan(const int* __restrict__ spc, int* __restrict__ sps, int* __restrict__ spcur){
  if (threadIdx.x==0 && blockIdx.x==0){
    int r=0;
    for (int s=0;s<NSm;s++){ sps[s]=r; spcur[s]=r; r+=spc[s]; }
    sps[NSm]=r;
  }
}

__global__ void k_spscatter(const int* __restrict__ sp, int* __restrict__ spcur,
                            int* __restrict__ order){
  __shared__ int h[NSm], base[NSm];
  int t = threadIdx.x;
  if (t < NSm) h[t]=0;
  __syncthreads();
  int i = blockIdx.x*256 + t;
  int s = sp[i];
  int lr = atomicAdd(&h[s], 1);
  __syncthreads();
  if (t < NSm) base[t] = atomicAdd(&spcur[t], h[t]);
  __syncthreads();
  order[base[s] + lr] = i;
}

// ---------- fused per-species MLP + epilogue A; FEW-BARRIER staging ----------
// R8-verified dataflow & values, restructured staging:
//   GEMM1: W1 staged in 4 chunks of K=96 (8 barriers)
//   GEMM2: whole W2 staged once (2 barriers)
//   GEMM3: whole Wn staged once (2 barriers)
// MFMA accumulation order identical to R8 (kb ascending) -> bit-identical.
// Hs/Is are wave-private (verified R9) -> no barriers around them.
__global__ __launch_bounds__(256) void k_mlp(
    const float* __restrict__ X, const int* __restrict__ order,
    const int* __restrict__ sps,
    const short* __restrict__ W1t, const short* __restrict__ W2t,
    const short* __restrict__ Wnt, const float* __restrict__ Wf,
    float* __restrict__ pre, float* __restrict__ nbr_g){
  const int s = blockIdx.y;
  const int s0 = sps[s];
  const int cnt = sps[s+1] - s0;
  const int row0 = blockIdx.x * 64;
  if (row0 >= cnt) return;

  __shared__ short Hs[64][200];     // 25.6 KB
  __shared__ short Is[64][104];     // 13.3 KB
  __shared__ short Ws[19968];       // 39.9 KB staging buffer
  __shared__ int aids[64];

  const int tid = threadIdx.x;
  if (tid < 64){
    int r = row0 + tid;
    aids[tid] = order[s0 + ((r < cnt) ? r : 0)];
  }
  __syncthreads();

  const int wave = tid >> 6, lane = tid & 63;
  const int lrow = lane & 15, quad = lane >> 4;
  const int arow = wave*16 + lrow;
  const float* xrow = X + (size_t)aids[arow]*NDm + quad*8;

  // preload & convert all A fragments (GEMM1) up front
  short8 afs[12];
  #pragma unroll
  for (int kb=0; kb<12; kb++){
    const float* p = xrow + kb*32;
    #pragma unroll
    for (int j=0;j<8;j++) afs[kb][j] = f2bf(p[j]);
  }

  // ---- GEMM1: [64,384]@[384,192]; 4 staged chunks of K=96
  const short* W1s = W1t + (size_t)s*NHm*NDm;
  float4v acc[12];
  #pragma unroll
  for (int i=0;i<12;i++){ acc[i][0]=0.f; acc[i][1]=0.f; acc[i][2]=0.f; acc[i][3]=0.f; }
  for (int kc=0; kc<4; kc++){
    __syncthreads();
    for (int e = tid; e < 192*12; e += 256){   // 192 cols x 12 short8 units
      int c = e / 12, u = e - c*12;
      *(short8*)(&Ws[c*104 + u*8]) = *(const short8*)(W1s + c*NDm + kc*96 + u*8);
    }
    __syncthreads();
    #pragma unroll
    for (int kb3=0; kb3<3; kb3++){
      short8 af = afs[kc*3 + kb3];
      #pragma unroll
      for (int ct=0; ct<12; ct++){
        short8 bfb = *(const short8*)(&Ws[(ct*16 + lrow)*104 + kb3*32 + quad*8]);
        acc[ct] = __builtin_amdgcn_mfma_f32_16x16x32_bf16(af, bfb, acc[ct], 0,0,0);
      }
    }
  }
  // gelu -> Hs (wave-private rows, no barrier)
  #pragma unroll
  for (int ct=0; ct<12; ct++){
    #pragma unroll
    for (int r=0;r<4;r++){
      Hs[wave*16 + quad*4 + r][ct*16 + lrow] = f2bf(gelu_t(acc[ct][r]));
    }
  }

  // ---- GEMM2: [64,192]@[192,96]; stage whole W2 once
  const short* W2s = W2t + (size_t)s*NFm*NHm;
  float4v acc2[6];
  #pragma unroll
  for (int i=0;i<6;i++){ acc2[i][0]=0.f; acc2[i][1]=0.f; acc2[i][2]=0.f; acc2[i][3]=0.f; }
  __syncthreads();
  for (int e = tid; e < 96*24; e += 256){      // 96 cols x 24 short8 units (K=192)
    int c = e / 24, u = e - c*24;
    *(short8*)(&Ws[c*200 + u*8]) = *(const short8*)(W2s + c*NHm + u*8);
  }
  __syncthreads();
  for (int kb=0; kb<6; kb++){
    short8 af2 = *(const short8*)(&Hs[wave*16 + lrow][kb*32 + quad*8]);
    #pragma unroll
    for (int ct=0; ct<6; ct++){
      short8 bfb = *(const short8*)(&Ws[(ct*16 + lrow)*200 + kb*32 + quad*8]);
      acc2[ct] = __builtin_amdgcn_mfma_f32_16x16x32_bf16(af2, bfb, acc2[ct], 0,0,0);
    }
  }
  // internal -> Is (wave-private)
  #pragma unroll
  for (int ct=0; ct<6; ct++){
    #pragma unroll
    for (int r=0;r<4;r++){
      Is[wave*16 + quad*4 + r][ct*16 + lrow] = f2bf(acc2[ct][r]);
    }
  }

  // ---- epilogue A (verified R8): pre = dot(internal_row, Wf[s][0:96])
  {
    float pr[4] = {0.f,0.f,0.f,0.f};
    #pragma unroll
    for (int ct=0; ct<6; ct++){
      float wv = Wf[s*2*NFm + ct*16 + lrow];
      #pragma unroll
      for (int r=0;r<4;r++) pr[r] += acc2[ct][r] * wv;
    }
    #pragma unroll
    for (int m=1; m<16; m<<=1){
      #pragma unroll
      for (int r=0;r<4;r++) pr[r] += __shfl_xor(pr[r], m, 64);
    }
    if (lrow == 0){
      #pragma unroll
      for (int r=0;r<4;r++){
        int row = wave*16 + quad*4 + r;
        if (row0 + row < cnt) pre[aids[row]] = pr[r];
      }
    }
  }

  // ---- GEMM3: [64,96]@[96,96]; stage whole Wn once
  const short* Wns = Wnt + (size_t)s*NFm*NFm;
  float4v acc3[6];
  #pragma unroll
  for (int i=0;i<6;i++){ acc3[i][0]=0.f; acc3[i][1]=0.f; acc3[i][2]=0.f; acc3[i][3]=0.f; }
  __syncthreads();
  for (int e = tid; e < 96*12; e += 256){      // 96 cols x 12 short8 units (K=96)
    int c = e / 12, u = e - c*12;
    *(short8*)(&Ws[c*104 + u*8]) = *(const short8*)(Wns + c*NFm + u*8);
  }
  __syncthreads();
  for (int kb=0; kb<3; kb++){
    short8 af3 = *(const short8*)(&Is[wave*16 + lrow][kb*32 + quad*8]);
    #pragma unroll
    for (int ct=0; ct<6; ct++){
      short8 bfb = *(const short8*)(&Ws[(ct*16 + lrow)*104 + kb*32 + quad*8]);
      acc3[ct] = __builtin_amdgcn_mfma_f32_16x16x32_bf16(af3, bfb, acc3[ct], 0,0,0);
    }
  }
  #pragma unroll
  for (int ct=0; ct<6; ct++){
    #pragma unroll
    for (int r=0;r<4;r++){
      int row = wave*16 + quad*4 + r, col = ct*16 + lrow;
      if (row0 + row < cnt) nbr_g[(size_t)aids[row]*NFm + col] = acc3[ct][r];
    }
  }
}

// ---------- per-atom nd4: one wave per atom, xor-shuffle reduce (verified R4-R10) ----------
__global__ void k_nd4(const float* __restrict__ nbr, const float* __restrict__ Wf,
                      float* __restrict__ nd4){
  int a = blockIdx.x*4 + (threadIdx.x >> 6);   // grid = NATOMS/4 exact
  int lane = threadIdx.x & 63;
  bool lo = lane < 32;
  const float* np = nbr + (size_t)a*NFm;
  float nv1 = np[lane];
  float nv2 = lo ? np[64+lane] : 0.f;
  const float* w0 = Wf + 0*2*NFm + NFm;
  const float* w1 = Wf + 1*2*NFm + NFm;
  const float* w2 = Wf + 2*2*NFm + NFm;
  const float* w3 = Wf + 3*2*NFm + NFm;
  float n0 = nv1*w0[lane] + (lo ? nv2*w0[64+lane] : 0.f);
  float n1 = nv1*w1[lane] + (lo ? nv2*w1[64+lane] : 0.f);
  float n2 = nv1*w2[lane] + (lo ? nv2*w2[64+lane] : 0.f);
  float n3 = nv1*w3[lane] + (lo ? nv2*w3[64+lane] : 0.f);
  #pragma unroll
  for (int m=1; m<64; m<<=1){
    n0 += __shfl_xor(n0, m, 64);
    n1 += __shfl_xor(n1, m, 64);
    n2 += __shfl_xor(n2, m, 64);
    n3 += __shfl_xor(n3, m, 64);
  }
  if (lane == 0){
    float4v v; v[0]=n0; v[1]=n1; v[2]=n2; v[3]=n3;
    *(float4v*)(nd4 + (size_t)a*4) = v;
  }
}

// ---------- message histogram: 2 messages/thread ----------
__global__ __launch_bounds__(1024) void k_hist(const int* __restrict__ ai,
                                               int* __restrict__ Hist){
  __shared__ int h[NBm];
  int t = threadIdx.x;
  if (t < NBm) h[t] = 0;
  __syncthreads();
  int base = blockIdx.x*2048;        // grid = HBLK2 exact
  atomicAdd(&h[ai[base + t] / NAm], 1);
  atomicAdd(&h[ai[base + 1024 + t] / NAm], 1);
  __syncthreads();
  if (t < NBm) Hist[blockIdx.x*NBm + t] = h[t];
}

// ---------- per-molecule scan over blocks (768 rows, 3/thread) ----------
__global__ void k_mscan(int* __restrict__ Hist, int* __restrict__ Tot){
  __shared__ int sums[256];
  int mol = blockIdx.x, t = threadIdx.x;
  int v[3]; int loc = 0;
  #pragma unroll
  for (int j=0;j<3;j++){ v[j] = Hist[(t*3+j)*NBm + mol]; loc += v[j]; }
  sums[t] = loc; __syncthreads();
  for (int off=1; off<256; off<<=1){
    int x = (t >= off) ? sums[t-off] : 0;
    __syncthreads();
    sums[t] += x;
    __syncthreads();
  }
  int run = sums[t] - loc;
  #pragma unroll
  for (int j=0;j<3;j++){ Hist[(t*3+j)*NBm + mol] = run; run += v[j]; }
  if (t == 255) Tot[mol] = run;
}

// ---------- exclusive scan of molecule totals ----------
__global__ void k_segscan(const int* __restrict__ Tot, int* __restrict__ Seg){
  __shared__ int s[256];
  int t = threadIdx.x;
  int v = Tot[t]; s[t] = v; __syncthreads();
  for (int off=1; off<256; off<<=1){
    int x = (t >= off) ? s[t-off] : 0;
    __syncthreads();
    s[t] += x;
    __syncthreads();
  }
  Seg[t] = s[t] - v;
  if (t == 255) Seg[256] = s[255];
}

// ---------- scatter messages, 2/thread, into molecule segments ----------
// Msg[pos] = { (other<<7) | dest_local , w }
__global__ __launch_bounds__(1024) void k_scatter(const int* __restrict__ ai,
    const float* __restrict__ dist, const float* __restrict__ pref,
    const float* __restrict__ fac, const int* __restrict__ Hist,
    const int* __restrict__ Seg, int2v* __restrict__ Msg){
  __shared__ int cnt[NBm];
  __shared__ int off[NBm];
  int t = threadIdx.x;
  if (t < NBm){ cnt[t] = 0; off[t] = Seg[t] + Hist[blockIdx.x*NBm + t]; }
  __syncthreads();
  int base = blockIdx.x*2048;
  float p = pref[0], fc = fac[0];
  #pragma unroll
  for (int half=0; half<2; half++){
    int m = base + half*1024 + t;
    int dest = ai[m];
    int other = ai[(m < NEe) ? m + NEe : m - NEe];
    int e = (m < NEe) ? m : m - NEe;
    float d = dist[e];
    float x = (CUTOFF_ - d) * (1.0f/CUTOFF_);
    x = fminf(fmaxf(x, 0.f), 1.f);
    float sc = x*x*x*(x*(6.f*x - 15.f) + 10.f);
    float w = p*p * expf(-fc*fc*d) * sc;
    int mol = dest / NAm, dl = dest - mol*NAm;
    int rank = atomicAdd(&cnt[mol], 1);
    int2v msg; msg[0] = (other << 7) | dl; msg[1] = __float_as_int(w);
    Msg[off[mol] + rank] = msg;
  }
}

// ---------- per-molecule accumulate + charge redistribution (1024 threads) ----------
__global__ __launch_bounds__(1024) void k_accum(const int* __restrict__ Seg,
    const int2v* __restrict__ Msg, const float* __restrict__ nd4,
    const int* __restrict__ sp, const float* __restrict__ pre,
    const float* __restrict__ tc, float* __restrict__ out){
  __shared__ float acc[NAm];
  __shared__ int spl[NAm];
  __shared__ float red[128];
  int mol = blockIdx.x, t = threadIdx.x;
  if (t < NAm){ acc[t] = 0.f; spl[t] = sp[mol*NAm + t]; }
  __syncthreads();
  int s0 = Seg[mol], s1 = Seg[mol+1];
  for (int i = s0 + t; i < s1; i += 1024){
    int2v kw = Msg[i];
    int key = kw[0]; float w = __int_as_float(kw[1]);
    int dl = key & 127, other = key >> 7;
    float val = w * nd4[(size_t)other*4 + spl[dl]];
    atomicAdd(&acc[dl], val);
  }
  __syncthreads();
  float pch = 0.f;
  if (t < NAm) pch = pre[mol*NAm + t] + acc[t];
  if (t < 128) red[t] = (t < NAm) ? pch : 0.f;
  __syncthreads();
  for (int o=64; o>0; o>>=1){
    if (t < o) red[t] += red[t + o];
    __syncthreads();
  }
  float sum = red[0];
  if (t < NAm){
    float c = pch + (tc[mol] - sum) * (1.0f/96.0f);
    out[mol*NAm + t] = (float)spl[t];            // species as float
    out[NATOMS + mol*NAm + t] = c;               // charges
    out[2*NATOMS + mol*NAm + t] = pch;           // precharges
  }
}

extern "C" void kernel_launch(void* const* d_in, const int* in_sizes, int n_in,
                              void* d_out, int out_size, void* d_ws, size_t ws_size,
                              hipStream_t stream) {
  const int*   species = (const int*)  d_in[0];
  const float* X       = (const float*)d_in[1];
  const int*   ai      = (const int*)  d_in[2];
  const float* dist    = (const float*)d_in[3];
  const float* tc      = (const float*)d_in[4];
  const float* W1      = (const float*)d_in[5];
  const float* W2      = (const float*)d_in[6];
  const float* Wn      = (const float*)d_in[7];
  const float* Wf      = (const float*)d_in[8];
  const float* pref    = (const float*)d_in[9];
  const float* fac     = (const float*)d_in[10];
  float* out = (float*)d_out;

  char* w = (char*)d_ws;
  auto alloc = [&](size_t bytes)->char*{
    char* p = w; w += (bytes + 255) & ~(size_t)255; return p;
  };
  int*   spc   = (int*)  alloc(64);
  int*   sps   = (int*)  alloc(64);
  int*   spcur = (int*)  alloc(64);
  int*   order = (int*)  alloc((size_t)NATOMS*4);
  float* nd4   = (float*)alloc((size_t)NATOMS*4*4);
  float* pre   = (float*)alloc((size_t)NATOMS*4);
  float* nbr   = (float*)alloc((size_t)NATOMS*NFm*4);
  short* W1t   = (short*)alloc((size_t)W1N*2);
  short* W2t   = (short*)alloc((size_t)W2N*2);
  short* Wnt   = (short*)alloc((size_t)WNN*2);
  int*   Hist  = (int*)  alloc((size_t)HBLK2*NBm*4);
  int*   Tot   = (int*)  alloc(1024);
  int*   Seg   = (int*)  alloc((NBm+1)*4);
  int2v* Msg   = (int2v*)alloc((size_t)NMSG*8);

  k_wprep<<<(W1N+W2N+WNN)/256, 256, 0, stream>>>(W1, W2, Wn, W1t, W2t, Wnt, spc);
  k_spcount<<<NATOMS/256, 256, 0, stream>>>(species, spc);
  k_spscan<<<1, 64, 0, stream>>>(spc, sps, spcur);
  k_spscatter<<<NATOMS/256, 256, 0, stream>>>(species, spcur, order);
  dim3 g(NATOMS/64, NSm);
  k_mlp<<<g, 256, 0, stream>>>(X, order, sps, W1t, W2t, Wnt, Wf, pre, nbr);
  k_nd4<<<NATOMS/4, 256, 0, stream>>>(nbr, Wf, nd4);
  k_hist<<<HBLK2, 1024, 0, stream>>>(ai, Hist);
  k_mscan<<<NBm, 256, 0, stream>>>(Hist, Tot);
  k_segscan<<<1, 256, 0, stream>>>(Tot, Seg);
  k_scatter<<<HBLK2, 1024, 0, stream>>>(ai, dist, pref, fac, Hist, Seg, Msg);
  k_accum<<<NBm, 1024, 0, stream>>>(Seg, Msg, nd4, species, pre, tc, out);
}